// Round 2
// baseline (527.802 us; speedup 1.0000x reference)
//
#include <hip/hip_runtime.h>
#include <hip/hip_bf16.h>

// B=1, S=256 (attention/LN axis), R=256, C=256, H=8, D=32.
// One workgroup per residue column r; 8 waves = 8 heads; fully fused.
// All GEMMs: v_mfma_f32_16x16x32_bf16, operand layouts chained so no
// fragment transposes are needed (compute Q^T/K^T; S^T = K-frags x Q^T-frags).
// No inline asm, no unions: bit_cast + pure C++ bf16 RNE conversion only.

using f32x4  = __attribute__((ext_vector_type(4))) float;
using bf16x8 = __attribute__((ext_vector_type(8))) short;

struct U4x { unsigned a0, a1, a2, a3; };
static_assert(sizeof(U4x) == sizeof(bf16x8), "frag size");

__device__ __forceinline__ f32x4 mfma16(bf16x8 a, bf16x8 b, f32x4 c){
  return __builtin_amdgcn_mfma_f32_16x16x32_bf16(a, b, c, 0, 0, 0);
}
// f32 -> bf16 (round-to-nearest-even), finite inputs only. Pure integer ops.
__device__ __forceinline__ unsigned f2bf(float f){
  unsigned u = __builtin_bit_cast(unsigned, f);
  u += 0x7fffu + ((u >> 16) & 1u);
  return u >> 16;
}
__device__ __forceinline__ unsigned pk2(float lo, float hi){
  return f2bf(lo) | (f2bf(hi) << 16);
}
__device__ __forceinline__ bf16x8 mk_frag(unsigned a0, unsigned a1, unsigned a2, unsigned a3){
  U4x t{a0, a1, a2, a3};
  return __builtin_bit_cast(bf16x8, t);
}
__device__ __forceinline__ float bf_lo(unsigned u){ return __builtin_bit_cast(float, u << 16); }
__device__ __forceinline__ float bf_hi(unsigned u){ return __builtin_bit_cast(float, u & 0xffff0000u); }
__device__ __forceinline__ float sigm(float x){ return 1.f / (1.f + __expf(-x)); }

// Swizzled byte address in the [256 rows][256 bf16] LDS tile (row stride 512B).
// XOR bits 4..7 with (row&15): bijective per row, keeps 16B alignment,
// breaks the 16-lane same-bank column pattern.
__device__ __forceinline__ int xaddr(int row, int cbyte){
  return (row << 9) + (cbyte ^ ((row & 15) << 4));
}
__device__ __forceinline__ bf16x8 lds_frag(const char* sm, int row, int cshort){
  return *(const bf16x8*)(sm + xaddr(row, cshort * 2));
}
__device__ __forceinline__ bf16x8 ldg_frag(const short* base, int row, int cshort){
  return *(const bf16x8*)(base + row * 256 + cshort);
}

// ---------------- prep: transpose + bf16-convert the 5 weight matrices -----
// ws (shorts): WqT[256][256], WkT, WvT, WgT  (T[n][c] = W[c][n], n = h*32+d)
//              WoT[256][256]                 (WoT[c][hd] = Wo[hd][c])
__global__ __launch_bounds__(256) void prep_weights(
    const float* __restrict__ Wq, const float* __restrict__ Wk,
    const float* __restrict__ Wv, const float* __restrict__ Wg,
    const float* __restrict__ Wo, short* __restrict__ ws)
{
  const int n = blockIdx.x, t = threadIdx.x;
  ws[0*65536 + n*256 + t] = (short)f2bf(Wq[t*256 + n]);
  ws[1*65536 + n*256 + t] = (short)f2bf(Wk[t*256 + n]);
  ws[2*65536 + n*256 + t] = (short)f2bf(Wv[t*256 + n]);
  ws[3*65536 + n*256 + t] = (short)f2bf(Wg[t*256 + n]);
  ws[4*65536 + n*256 + t] = (short)f2bf(Wo[t*256 + n]);
}

// ---------------- per-half attention (queries [IB, IB+128)) ----------------
// Produces gated-output bf16 D-frag pairs: go0 = d in [hbase,hbase+16),
// go1 = d in [hbase+16,hbase+32); go*[it][0] = rows 4g+{0,1}, [1] = 4g+{2,3}.
template<int IB>
__device__ __forceinline__ void attn_half(
    const char* sm, const short* WqT, const short* WkT,
    const short* WvT, const short* WgT,
    int hbase, int g, int c15, float bg0, float bg1,
    unsigned (&go0)[8][2], unsigned (&go1)[8][2])
{
  const float scl = 0.17677669529663687f;   // 1/sqrt(32), folded into Q
  // A) Q^T = WqT @ X^T   (D-frag rows = d, cols = i)
  //    G   = sigmoid(X @ Wg + bg)  (D-frag rows = i, cols = hd)
  unsigned qTa[8][2], qTb[8][2], gfa[8][2], gfb[8][2];
  #pragma unroll
  for (int nt = 0; nt < 8; nt++){
    f32x4 aq0{0,0,0,0}, aq1{0,0,0,0}, ag0{0,0,0,0}, ag1{0,0,0,0};
    #pragma unroll
    for (int kk = 0; kk < 8; kk++){
      const int cs = 32 * kk + 8 * g;
      bf16x8 bx = lds_frag(sm, IB + nt * 16 + c15, cs);
      aq0 = mfma16(ldg_frag(WqT, hbase + c15,      cs), bx, aq0);
      aq1 = mfma16(ldg_frag(WqT, hbase + 16 + c15, cs), bx, aq1);
      ag0 = mfma16(bx, ldg_frag(WgT, hbase + c15,      cs), ag0);
      ag1 = mfma16(bx, ldg_frag(WgT, hbase + 16 + c15, cs), ag1);
    }
    qTa[nt][0] = pk2(aq0.x*scl, aq0.y*scl); qTa[nt][1] = pk2(aq0.z*scl, aq0.w*scl);
    qTb[nt][0] = pk2(aq1.x*scl, aq1.y*scl); qTb[nt][1] = pk2(aq1.z*scl, aq1.w*scl);
    gfa[nt][0] = pk2(sigm(ag0.x+bg0), sigm(ag0.y+bg0));
    gfa[nt][1] = pk2(sigm(ag0.z+bg0), sigm(ag0.w+bg0));
    gfb[nt][0] = pk2(sigm(ag1.x+bg1), sigm(ag1.y+bg1));
    gfb[nt][1] = pk2(sigm(ag1.z+bg1), sigm(ag1.w+bg1));
  }

  // B) flash over j-tiles of 32: K^T,V on the fly; S^T = K x Q^T; online SM; PV
  float m_[8], l_[8];
  f32x4 o_[8][2];
  #pragma unroll
  for (int i2 = 0; i2 < 8; i2++){
    m_[i2] = -1e30f; l_[i2] = 0.f;
    o_[i2][0] = f32x4{0,0,0,0}; o_[i2][1] = f32x4{0,0,0,0};
  }
  for (int jt = 0; jt < 8; jt++){
    const int jb = jt * 32;
    f32x4 kt00{0,0,0,0}, kt01{0,0,0,0}, kt10{0,0,0,0}, kt11{0,0,0,0};
    f32x4 va00{0,0,0,0}, va01{0,0,0,0}, va10{0,0,0,0}, va11{0,0,0,0};
    #pragma unroll
    for (int kk = 0; kk < 8; kk++){
      const int cs = 32 * kk + 8 * g;
      bf16x8 bx0 = lds_frag(sm, jb + c15,      cs);  // serves K^T(B) and V(A)
      bf16x8 bx1 = lds_frag(sm, jb + 16 + c15, cs);
      bf16x8 wk0 = ldg_frag(WkT, hbase + c15,      cs);
      bf16x8 wk1 = ldg_frag(WkT, hbase + 16 + c15, cs);
      bf16x8 wv0 = ldg_frag(WvT, hbase + c15,      cs);
      bf16x8 wv1 = ldg_frag(WvT, hbase + 16 + c15, cs);
      kt00 = mfma16(wk0, bx0, kt00);   // K^T[d 0:16 ][j 0:16 ]
      kt01 = mfma16(wk0, bx1, kt01);   // K^T[d 0:16 ][j 16:32]
      kt10 = mfma16(wk1, bx0, kt10);   // K^T[d 16:32][j 0:16 ]
      kt11 = mfma16(wk1, bx1, kt11);   // K^T[d 16:32][j 16:32]
      va00 = mfma16(bx0, wv0, va00);   // V[j 0:16 ][d 0:16 ]
      va01 = mfma16(bx0, wv1, va01);   // V[j 0:16 ][d 16:32]
      va10 = mfma16(bx1, wv0, va10);   // V[j 16:32][d 0:16 ]
      va11 = mfma16(bx1, wv1, va11);   // V[j 16:32][d 16:32]
    }
    bf16x8 aS0 = mk_frag(pk2(kt00.x,kt00.y), pk2(kt00.z,kt00.w),
                         pk2(kt10.x,kt10.y), pk2(kt10.z,kt10.w));
    bf16x8 aS1 = mk_frag(pk2(kt01.x,kt01.y), pk2(kt01.z,kt01.w),
                         pk2(kt11.x,kt11.y), pk2(kt11.z,kt11.w));
    bf16x8 bV0 = mk_frag(pk2(va00.x,va00.y), pk2(va00.z,va00.w),
                         pk2(va10.x,va10.y), pk2(va10.z,va10.w));
    bf16x8 bV1 = mk_frag(pk2(va01.x,va01.y), pk2(va01.z,va01.w),
                         pk2(va11.x,va11.y), pk2(va11.z,va11.w));
    #pragma unroll
    for (int it = 0; it < 8; it++){
      bf16x8 bS = mk_frag(qTa[it][0], qTa[it][1], qTb[it][0], qTb[it][1]);
      f32x4 z{0,0,0,0};
      f32x4 s0 = mfma16(aS0, bS, z);   // lane: S[i = c15][j = jb+4g+jj]
      f32x4 s1 = mfma16(aS1, bS, z);   //       S[i = c15][j = jb+16+4g+jj]
      float pm = fmaxf(fmaxf(fmaxf(s0.x,s0.y), fmaxf(s0.z,s0.w)),
                       fmaxf(fmaxf(s1.x,s1.y), fmaxf(s1.z,s1.w)));
      pm = fmaxf(pm, __shfl_xor(pm, 16));
      pm = fmaxf(pm, __shfl_xor(pm, 32));
      const float mnew = fmaxf(m_[it], pm);
      const float corr = __expf(m_[it] - mnew);
      float e0=__expf(s0.x-mnew), e1=__expf(s0.y-mnew), e2=__expf(s0.z-mnew), e3=__expf(s0.w-mnew);
      float e4=__expf(s1.x-mnew), e5=__expf(s1.y-mnew), e6=__expf(s1.z-mnew), e7=__expf(s1.w-mnew);
      float rs = ((e0+e1)+(e2+e3)) + ((e4+e5)+(e6+e7));
      rs += __shfl_xor(rs, 16); rs += __shfl_xor(rs, 32);
      l_[it] = l_[it] * corr + rs;
      m_[it] = mnew;
      bf16x8 aP = mk_frag(pk2(e0,e1), pk2(e2,e3), pk2(e4,e5), pk2(e6,e7));
      #pragma unroll
      for (int jj = 0; jj < 4; jj++){
        const float cj = __shfl(corr, 4 * g + jj);   // O-frag row i = 4g+jj
        o_[it][0][jj] *= cj;
        o_[it][1][jj] *= cj;
      }
      o_[it][0] = mfma16(aP, bV0, o_[it][0]);
      o_[it][1] = mfma16(aP, bV1, o_[it][1]);
    }
  }

  // C) finalize: O/l, gate, pack bf16
  #pragma unroll
  for (int it = 0; it < 8; it++){
    float inv[4];
    #pragma unroll
    for (int jj = 0; jj < 4; jj++) inv[jj] = 1.f / __shfl(l_[it], 4 * g + jj);
    float ga0[4] = {bf_lo(gfa[it][0]), bf_hi(gfa[it][0]), bf_lo(gfa[it][1]), bf_hi(gfa[it][1])};
    float ga1[4] = {bf_lo(gfb[it][0]), bf_hi(gfb[it][0]), bf_lo(gfb[it][1]), bf_hi(gfb[it][1])};
    float t0 = o_[it][0][0]*inv[0]*ga0[0], t1 = o_[it][0][1]*inv[1]*ga0[1];
    float t2 = o_[it][0][2]*inv[2]*ga0[2], t3 = o_[it][0][3]*inv[3]*ga0[3];
    float u0 = o_[it][1][0]*inv[0]*ga1[0], u1 = o_[it][1][1]*inv[1]*ga1[1];
    float u2 = o_[it][1][2]*inv[2]*ga1[2], u3 = o_[it][1][3]*inv[3]*ga1[3];
    go0[it][0] = pk2(t0,t1); go0[it][1] = pk2(t2,t3);
    go1[it][0] = pk2(u0,u1); go1[it][1] = pk2(u2,u3);
  }
}

__device__ __forceinline__ void store_go(char* sm, int i0, int hd, unsigned v0, unsigned v1){
  *(short*)(sm + xaddr(i0 + 0, hd * 2)) = (short)(v0 & 0xffffu);
  *(short*)(sm + xaddr(i0 + 1, hd * 2)) = (short)(v0 >> 16);
  *(short*)(sm + xaddr(i0 + 2, hd * 2)) = (short)(v1 & 0xffffu);
  *(short*)(sm + xaddr(i0 + 3, hd * 2)) = (short)(v1 >> 16);
}

// ---------------- main fused kernel ----------------------------------------
__global__ __launch_bounds__(512) void msa_attn(
    const float* __restrict__ msa, const float* __restrict__ lnw,
    const float* __restrict__ lnb, const float* __restrict__ bg,
    const float* __restrict__ bo,  const short* __restrict__ wsW,
    float* __restrict__ out)
{
  extern __shared__ __align__(16) char sm[];   // [0,131072): x / GO tile (bf16, swizzled)
  float* muA = (float*)(sm + 131072);          // 256 f32
  float* rsA = muA + 256;                      // 256 f32

  const int r   = blockIdx.x;
  const int tid = threadIdx.x;
  const float* msa_r = msa + r * 256;          // msa[s][r][c] = msa_r[s*65536 + c]

  // ---- phase 1a: LN stats over s for each c ----
  {
    float s0 = 0.f, s1 = 0.f;
    const int c = tid & 255, sh = tid >> 8;
    const float* p = msa_r + (sh * 128) * 65536 + c;
    for (int i = 0; i < 128; i++){ float v = p[i * 65536]; s0 += v; s1 += v * v; }
    float* sb = (float*)sm;                    // transient, overlaps x tile
    sb[tid] = s0; sb[512 + tid] = s1;
    __syncthreads();
    if (tid < 256){
      float tot = sb[tid] + sb[256 + tid];
      float sq  = sb[512 + tid] + sb[768 + tid];
      float mu  = tot * (1.f / 256.f);
      float var = fmaxf(sq * (1.f / 256.f) - mu * mu, 0.f);
      muA[tid] = mu; rsA[tid] = rsqrtf(var + 1e-5f);
    }
    __syncthreads();
  }
  // ---- phase 1b: normalized x tile (bf16, swizzled) ----
  {
    const int c0 = (tid & 31) * 8;
    float mu0[8], rs0[8];
    #pragma unroll
    for (int k = 0; k < 8; k++){ mu0[k] = muA[c0 + k]; rs0[k] = rsA[c0 + k]; }
    for (int itr = 0; itr < 16; itr++){
      const int s = itr * 16 + (tid >> 5);
      const float w = lnw[s], b = lnb[s];
      const float* rp = msa_r + s * 65536 + c0;
      f32x4 v0 = *(const f32x4*)rp;
      f32x4 v1 = *(const f32x4*)(rp + 4);
      U4x q{pk2((v0.x-mu0[0])*rs0[0]*w+b, (v0.y-mu0[1])*rs0[1]*w+b),
            pk2((v0.z-mu0[2])*rs0[2]*w+b, (v0.w-mu0[3])*rs0[3]*w+b),
            pk2((v1.x-mu0[4])*rs0[4]*w+b, (v1.y-mu0[5])*rs0[5]*w+b),
            pk2((v1.z-mu0[6])*rs0[6]*w+b, (v1.w-mu0[7])*rs0[7]*w+b)};
      *(U4x*)(sm + xaddr(s, c0 * 2)) = q;
    }
    __syncthreads();
  }

  // ---- phase 2: per-wave (= per-head) attention, two query halves ----
  const int wid  = tid >> 6;                   // head
  const int lane = tid & 63;
  const int g = lane >> 4, c15 = lane & 15;
  const short* WqT = wsW;
  const short* WkT = wsW + 65536;
  const short* WvT = wsW + 2 * 65536;
  const short* WgT = wsW + 3 * 65536;
  const short* WoT = wsW + 4 * 65536;
  const int hbase = wid * 32;
  const float bg0 = bg[hbase + c15], bg1 = bg[hbase + 16 + c15];

  unsigned g00[8][2], g01[8][2], g10[8][2], g11[8][2];
  attn_half<0>  (sm, WqT, WkT, WvT, WgT, hbase, g, c15, bg0, bg1, g00, g01);
  attn_half<128>(sm, WqT, WkT, WvT, WgT, hbase, g, c15, bg0, bg1, g10, g11);

  __syncthreads();   // x tile dead; reuse LDS for GO [i][hd], same swizzle
  #pragma unroll
  for (int it = 0; it < 8; it++){
    const int ia = it * 16 + g * 4, ib = 128 + it * 16 + g * 4;
    store_go(sm, ia, hbase + c15,      g00[it][0], g00[it][1]);
    store_go(sm, ia, hbase + 16 + c15, g01[it][0], g01[it][1]);
    store_go(sm, ib, hbase + c15,      g10[it][0], g10[it][1]);
    store_go(sm, ib, hbase + 16 + c15, g11[it][0], g11[it][1]);
  }
  __syncthreads();

  // ---- phase 3: out = GO @ Wo + bo; store out[s][r][c] ----
  #pragma unroll
  for (int t2 = 0; t2 < 2; t2++){
    const int it = wid * 2 + t2;               // i-tile 0..15
    bf16x8 aGO[8];
    #pragma unroll
    for (int kk = 0; kk < 8; kk++) aGO[kk] = lds_frag(sm, it * 16 + c15, 32 * kk + 8 * g);
    for (int ct = 0; ct < 16; ct++){
      f32x4 acc{0,0,0,0};
      #pragma unroll
      for (int kk = 0; kk < 8; kk++)
        acc = mfma16(aGO[kk], ldg_frag(WoT, ct * 16 + c15, 32 * kk + 8 * g), acc);
      const float bov = bo[ct * 16 + c15];
      const int i0 = it * 16 + g * 4;
      const int cc = ct * 16 + c15;
      out[(i0 + 0) * 65536 + r * 256 + cc] = acc.x + bov;
      out[(i0 + 1) * 65536 + r * 256 + cc] = acc.y + bov;
      out[(i0 + 2) * 65536 + r * 256 + cc] = acc.z + bov;
      out[(i0 + 3) * 65536 + r * 256 + cc] = acc.w + bov;
    }
  }
}

extern "C" void kernel_launch(void* const* d_in, const int* in_sizes, int n_in,
                              void* d_out, int out_size, void* d_ws, size_t ws_size,
                              hipStream_t stream)
{
  (void)in_sizes; (void)n_in; (void)out_size; (void)ws_size;
  const float* msa = (const float*)d_in[0];
  const float* lnw = (const float*)d_in[1];
  const float* lnb = (const float*)d_in[2];
  const float* Wq  = (const float*)d_in[3];
  const float* Wk  = (const float*)d_in[4];
  const float* Wv  = (const float*)d_in[5];
  const float* Wg  = (const float*)d_in[6];
  const float* bg  = (const float*)d_in[7];
  const float* Wo  = (const float*)d_in[8];
  const float* bo  = (const float*)d_in[9];
  short* ws = (short*)d_ws;                    // needs 5*65536*2 = 640 KB scratch

  prep_weights<<<256, 256, 0, stream>>>(Wq, Wk, Wv, Wg, Wo, ws);
  msa_attn<<<256, 512, 133120, stream>>>(msa, lnw, lnb, bg, bo, ws, (float*)d_out);
}

// Round 3
// 393.764 us; speedup vs baseline: 1.3404x; 1.3404x over previous
//
#include <hip/hip_runtime.h>
#include <hip/hip_bf16.h>

// B=1, S=256 (attention/LN axis), R=256, C=256, H=8, D=32.
// One workgroup per residue column r; 8 waves = 8 heads; fully fused.
// Round 3: K^T/V fragments register-resident (computed once per wave);
// flash loop is pure-register MFMA+VALU; weight frags hoisted out of
// inner loops. Numerics identical to round 2 except gating uses f32 G
// (more accurate).

using f32x4  = __attribute__((ext_vector_type(4))) float;
using bf16x8 = __attribute__((ext_vector_type(8))) short;

struct U4x { unsigned a0, a1, a2, a3; };
static_assert(sizeof(U4x) == sizeof(bf16x8), "frag size");

__device__ __forceinline__ f32x4 mfma16(bf16x8 a, bf16x8 b, f32x4 c){
  return __builtin_amdgcn_mfma_f32_16x16x32_bf16(a, b, c, 0, 0, 0);
}
// f32 -> bf16 RNE, finite inputs only.
__device__ __forceinline__ unsigned f2bf(float f){
  unsigned u = __builtin_bit_cast(unsigned, f);
  u += 0x7fffu + ((u >> 16) & 1u);
  return u >> 16;
}
__device__ __forceinline__ unsigned pk2(float lo, float hi){
  return f2bf(lo) | (f2bf(hi) << 16);
}
__device__ __forceinline__ bf16x8 mk_frag(unsigned a0, unsigned a1, unsigned a2, unsigned a3){
  U4x t{a0, a1, a2, a3};
  return __builtin_bit_cast(bf16x8, t);
}
__device__ __forceinline__ float sigm(float x){ return 1.f / (1.f + __expf(-x)); }

// Swizzled byte address in the [256 rows][256 bf16] LDS tile (row stride 512B).
__device__ __forceinline__ int xaddr(int row, int cbyte){
  return (row << 9) + (cbyte ^ ((row & 15) << 4));
}
__device__ __forceinline__ bf16x8 lds_frag(const char* sm, int row, int cshort){
  return *(const bf16x8*)(sm + xaddr(row, cshort * 2));
}
__device__ __forceinline__ bf16x8 ldg_frag(const short* base, int row, int cshort){
  return *(const bf16x8*)(base + row * 256 + cshort);
}

// ---------------- prep: transpose + bf16-convert the 5 weight matrices -----
// ws (shorts): WqT[256][256], WkT, WvT, WgT  (T[n][c] = W[c][n], n = h*32+d)
//              WoT[256][256]                 (WoT[c][hd] = Wo[hd][c])
__global__ __launch_bounds__(256) void prep_weights(
    const float* __restrict__ Wq, const float* __restrict__ Wk,
    const float* __restrict__ Wv, const float* __restrict__ Wg,
    const float* __restrict__ Wo, short* __restrict__ ws)
{
  const int n = blockIdx.x, t = threadIdx.x;
  ws[0*65536 + n*256 + t] = (short)f2bf(Wq[t*256 + n]);
  ws[1*65536 + n*256 + t] = (short)f2bf(Wk[t*256 + n]);
  ws[2*65536 + n*256 + t] = (short)f2bf(Wv[t*256 + n]);
  ws[3*65536 + n*256 + t] = (short)f2bf(Wg[t*256 + n]);
  ws[4*65536 + n*256 + t] = (short)f2bf(Wo[t*256 + n]);
}

// ---------------- per-half attention (queries [IB, IB+128)) ----------------
// K^T/V frags are register-resident inputs; flash loop touches no memory.
template<int IB>
__device__ __forceinline__ void attn_half(
    const char* sm, const short* WqT, const short* WgT,
    const bf16x8 (&kfr)[8][2], const bf16x8 (&vfr)[8][2],
    int hbase, int g, int c15, float bg0, float bg1,
    unsigned (&go0)[8][2], unsigned (&go1)[8][2])
{
  const float scl = 0.17677669529663687f;   // 1/sqrt(32), folded into Q
  // A) Q^T = WqT @ X^T, weight frags hoisted per d-row (8 live at a time)
  unsigned qTa[8][2], qTb[8][2];
  #pragma unroll
  for (int dr = 0; dr < 2; dr++){
    bf16x8 wq[8];
    #pragma unroll
    for (int kk = 0; kk < 8; kk++) wq[kk] = ldg_frag(WqT, hbase + 16*dr + c15, 32*kk + 8*g);
    #pragma unroll
    for (int nt = 0; nt < 8; nt++){
      f32x4 a{0,0,0,0};
      #pragma unroll
      for (int kk = 0; kk < 8; kk++)
        a = mfma16(wq[kk], lds_frag(sm, IB + nt*16 + c15, 32*kk + 8*g), a);
      if (dr == 0){ qTa[nt][0] = pk2(a.x*scl, a.y*scl); qTa[nt][1] = pk2(a.z*scl, a.w*scl); }
      else        { qTb[nt][0] = pk2(a.x*scl, a.y*scl); qTb[nt][1] = pk2(a.z*scl, a.w*scl); }
    }
  }

  // B) flash over j-tiles: S^T = K-frags x Q^T-frags; online SM; PV. Pure reg.
  float m_[8], l_[8];
  f32x4 o_[8][2];
  #pragma unroll
  for (int i2 = 0; i2 < 8; i2++){
    m_[i2] = -1e30f; l_[i2] = 0.f;
    o_[i2][0] = f32x4{0,0,0,0}; o_[i2][1] = f32x4{0,0,0,0};
  }
  #pragma unroll
  for (int jt = 0; jt < 8; jt++){
    #pragma unroll
    for (int it = 0; it < 8; it++){
      bf16x8 bS = mk_frag(qTa[it][0], qTa[it][1], qTb[it][0], qTb[it][1]);
      f32x4 z{0,0,0,0};
      f32x4 s0 = mfma16(kfr[jt][0], bS, z);   // S[i=c15][j = 32jt+4g+jj]
      f32x4 s1 = mfma16(kfr[jt][1], bS, z);   // S[i=c15][j = 32jt+16+4g+jj]
      float pm = fmaxf(fmaxf(fmaxf(s0.x,s0.y), fmaxf(s0.z,s0.w)),
                       fmaxf(fmaxf(s1.x,s1.y), fmaxf(s1.z,s1.w)));
      pm = fmaxf(pm, __shfl_xor(pm, 16));
      pm = fmaxf(pm, __shfl_xor(pm, 32));
      const float mnew = fmaxf(m_[it], pm);
      const float corr = __expf(m_[it] - mnew);
      float e0=__expf(s0.x-mnew), e1=__expf(s0.y-mnew), e2=__expf(s0.z-mnew), e3=__expf(s0.w-mnew);
      float e4=__expf(s1.x-mnew), e5=__expf(s1.y-mnew), e6=__expf(s1.z-mnew), e7=__expf(s1.w-mnew);
      float rs = ((e0+e1)+(e2+e3)) + ((e4+e5)+(e6+e7));
      rs += __shfl_xor(rs, 16); rs += __shfl_xor(rs, 32);
      l_[it] = l_[it] * corr + rs;
      m_[it] = mnew;
      bf16x8 aP = mk_frag(pk2(e0,e1), pk2(e2,e3), pk2(e4,e5), pk2(e6,e7));
      #pragma unroll
      for (int jj = 0; jj < 4; jj++){
        const float cj = __shfl(corr, 4*g + jj);   // O-frag row i = 4g+jj
        o_[it][0][jj] *= cj;
        o_[it][1][jj] *= cj;
      }
      o_[it][0] = mfma16(aP, vfr[jt][0], o_[it][0]);
      o_[it][1] = mfma16(aP, vfr[jt][1], o_[it][1]);
    }
  }

  // C) G = sigmoid(X@Wg + bg) (f32), normalize O, gate, pack bf16
  #pragma unroll
  for (int dr = 0; dr < 2; dr++){
    bf16x8 wg[8];
    #pragma unroll
    for (int kk = 0; kk < 8; kk++) wg[kk] = ldg_frag(WgT, hbase + 16*dr + c15, 32*kk + 8*g);
    const float bgd = dr ? bg1 : bg0;
    #pragma unroll
    for (int nt = 0; nt < 8; nt++){
      f32x4 a{0,0,0,0};
      #pragma unroll
      for (int kk = 0; kk < 8; kk++)
        a = mfma16(lds_frag(sm, IB + nt*16 + c15, 32*kk + 8*g), wg[kk], a);
      float inv[4];
      #pragma unroll
      for (int jj = 0; jj < 4; jj++) inv[jj] = 1.f / __shfl(l_[nt], 4*g + jj);
      const float ga0 = sigm(a.x + bgd), ga1 = sigm(a.y + bgd);
      const float ga2 = sigm(a.z + bgd), ga3 = sigm(a.w + bgd);
      const f32x4 ov = o_[nt][dr];
      const unsigned w0 = pk2(ov[0]*inv[0]*ga0, ov[1]*inv[1]*ga1);
      const unsigned w1 = pk2(ov[2]*inv[2]*ga2, ov[3]*inv[3]*ga3);
      if (dr == 0){ go0[nt][0] = w0; go0[nt][1] = w1; }
      else        { go1[nt][0] = w0; go1[nt][1] = w1; }
    }
  }
}

__device__ __forceinline__ void store_go(char* sm, int i0, int hd, unsigned v0, unsigned v1){
  *(short*)(sm + xaddr(i0 + 0, hd * 2)) = (short)(v0 & 0xffffu);
  *(short*)(sm + xaddr(i0 + 1, hd * 2)) = (short)(v0 >> 16);
  *(short*)(sm + xaddr(i0 + 2, hd * 2)) = (short)(v1 & 0xffffu);
  *(short*)(sm + xaddr(i0 + 3, hd * 2)) = (short)(v1 >> 16);
}

// ---------------- main fused kernel ----------------------------------------
__global__ __launch_bounds__(512) void msa_attn(
    const float* __restrict__ msa, const float* __restrict__ lnw,
    const float* __restrict__ lnb, const float* __restrict__ bg,
    const float* __restrict__ bo,  const short* __restrict__ wsW,
    float* __restrict__ out)
{
  extern __shared__ __align__(16) char sm[];   // [0,131072): x / GO tile (bf16, swizzled)
  float* muA = (float*)(sm + 131072);          // 256 f32
  float* rsA = muA + 256;                      // 256 f32

  const int r   = blockIdx.x;
  const int tid = threadIdx.x;
  const float* msa_r = msa + r * 256;          // msa[s][r][c] = msa_r[s*65536 + c]

  // ---- phase 1a: LN stats over s for each c ----
  {
    float s0 = 0.f, s1 = 0.f;
    const int c = tid & 255, sh = tid >> 8;
    const float* p = msa_r + (sh * 128) * 65536 + c;
    #pragma unroll 8
    for (int i = 0; i < 128; i++){ float v = p[i * 65536]; s0 += v; s1 += v * v; }
    float* sb = (float*)sm;                    // transient, overlaps x tile
    sb[tid] = s0; sb[512 + tid] = s1;
    __syncthreads();
    if (tid < 256){
      float tot = sb[tid] + sb[256 + tid];
      float sq  = sb[512 + tid] + sb[768 + tid];
      float mu  = tot * (1.f / 256.f);
      float var = fmaxf(sq * (1.f / 256.f) - mu * mu, 0.f);
      muA[tid] = mu; rsA[tid] = rsqrtf(var + 1e-5f);
    }
    __syncthreads();
  }
  // ---- phase 1b: normalized x tile (bf16, swizzled) ----
  {
    const int c0 = (tid & 31) * 8;
    float mu0[8], rs0[8];
    #pragma unroll
    for (int k = 0; k < 8; k++){ mu0[k] = muA[c0 + k]; rs0[k] = rsA[c0 + k]; }
    for (int itr = 0; itr < 16; itr++){
      const int s = itr * 16 + (tid >> 5);
      const float w = lnw[s], b = lnb[s];
      const float* rp = msa_r + s * 65536 + c0;
      f32x4 v0 = *(const f32x4*)rp;
      f32x4 v1 = *(const f32x4*)(rp + 4);
      U4x q{pk2((v0.x-mu0[0])*rs0[0]*w+b, (v0.y-mu0[1])*rs0[1]*w+b),
            pk2((v0.z-mu0[2])*rs0[2]*w+b, (v0.w-mu0[3])*rs0[3]*w+b),
            pk2((v1.x-mu0[4])*rs0[4]*w+b, (v1.y-mu0[5])*rs0[5]*w+b),
            pk2((v1.z-mu0[6])*rs0[6]*w+b, (v1.w-mu0[7])*rs0[7]*w+b)};
      *(U4x*)(sm + xaddr(s, c0 * 2)) = q;
    }
    __syncthreads();
  }

  // ---- phase 2: per-wave (= per-head) attention ----
  const int wid  = tid >> 6;                   // head
  const int lane = tid & 63;
  const int g = lane >> 4, c15 = lane & 15;
  const short* WqT = wsW;
  const short* WkT = wsW + 65536;
  const short* WvT = wsW + 2 * 65536;
  const short* WgT = wsW + 3 * 65536;
  const short* WoT = wsW + 4 * 65536;
  const int hbase = wid * 32;
  const float bg0 = bg[hbase + c15], bg1 = bg[hbase + 16 + c15];

  // ---- KV-gen ONCE into registers (kfr/vfr persist through both halves) ----
  bf16x8 kfr[8][2], vfr[8][2];
  #pragma unroll
  for (int ch = 0; ch < 2; ch++){              // j-tile chunks of 4
    f32x4 kt[4][2][2], va[4][2][2];            // [j4][drow|jrow][jcol|dcol]
    #pragma unroll
    for (int a = 0; a < 4; a++)
      #pragma unroll
      for (int b = 0; b < 2; b++)
        #pragma unroll
        for (int d = 0; d < 2; d++){ kt[a][b][d] = f32x4{0,0,0,0}; va[a][b][d] = f32x4{0,0,0,0}; }
    #pragma unroll
    for (int kk = 0; kk < 8; kk++){
      const int cs = 32*kk + 8*g;
      bf16x8 wk0 = ldg_frag(WkT, hbase + c15,      cs);
      bf16x8 wk1 = ldg_frag(WkT, hbase + 16 + c15, cs);
      bf16x8 wv0 = ldg_frag(WvT, hbase + c15,      cs);
      bf16x8 wv1 = ldg_frag(WvT, hbase + 16 + c15, cs);
      #pragma unroll
      for (int j4 = 0; j4 < 4; j4++){
        const int jb = (ch*4 + j4) * 32;
        bf16x8 bx0 = lds_frag(sm, jb + c15,      cs);
        bf16x8 bx1 = lds_frag(sm, jb + 16 + c15, cs);
        kt[j4][0][0] = mfma16(wk0, bx0, kt[j4][0][0]);   // K^T[d 0:16 ][j 0:16 ]
        kt[j4][0][1] = mfma16(wk0, bx1, kt[j4][0][1]);   // K^T[d 0:16 ][j 16:32]
        kt[j4][1][0] = mfma16(wk1, bx0, kt[j4][1][0]);   // K^T[d 16:32][j 0:16 ]
        kt[j4][1][1] = mfma16(wk1, bx1, kt[j4][1][1]);   // K^T[d 16:32][j 16:32]
        va[j4][0][0] = mfma16(bx0, wv0, va[j4][0][0]);   // V[j 0:16 ][d 0:16 ]
        va[j4][0][1] = mfma16(bx0, wv1, va[j4][0][1]);   // V[j 0:16 ][d 16:32]
        va[j4][1][0] = mfma16(bx1, wv0, va[j4][1][0]);   // V[j 16:32][d 0:16 ]
        va[j4][1][1] = mfma16(bx1, wv1, va[j4][1][1]);   // V[j 16:32][d 16:32]
      }
    }
    #pragma unroll
    for (int j4 = 0; j4 < 4; j4++){
      const int jt = ch*4 + j4;
      kfr[jt][0] = mk_frag(pk2(kt[j4][0][0].x,kt[j4][0][0].y), pk2(kt[j4][0][0].z,kt[j4][0][0].w),
                           pk2(kt[j4][1][0].x,kt[j4][1][0].y), pk2(kt[j4][1][0].z,kt[j4][1][0].w));
      kfr[jt][1] = mk_frag(pk2(kt[j4][0][1].x,kt[j4][0][1].y), pk2(kt[j4][0][1].z,kt[j4][0][1].w),
                           pk2(kt[j4][1][1].x,kt[j4][1][1].y), pk2(kt[j4][1][1].z,kt[j4][1][1].w));
      vfr[jt][0] = mk_frag(pk2(va[j4][0][0].x,va[j4][0][0].y), pk2(va[j4][0][0].z,va[j4][0][0].w),
                           pk2(va[j4][1][0].x,va[j4][1][0].y), pk2(va[j4][1][0].z,va[j4][1][0].w));
      vfr[jt][1] = mk_frag(pk2(va[j4][0][1].x,va[j4][0][1].y), pk2(va[j4][0][1].z,va[j4][0][1].w),
                           pk2(va[j4][1][1].x,va[j4][1][1].y), pk2(va[j4][1][1].z,va[j4][1][1].w));
    }
  }

  unsigned g00[8][2], g01[8][2], g10[8][2], g11[8][2];
  attn_half<0>  (sm, WqT, WgT, kfr, vfr, hbase, g, c15, bg0, bg1, g00, g01);
  attn_half<128>(sm, WqT, WgT, kfr, vfr, hbase, g, c15, bg0, bg1, g10, g11);

  __syncthreads();   // x tile dead; reuse LDS for GO [i][hd], same swizzle
  #pragma unroll
  for (int it = 0; it < 8; it++){
    const int ia = it * 16 + g * 4, ib = 128 + it * 16 + g * 4;
    store_go(sm, ia, hbase + c15,      g00[it][0], g00[it][1]);
    store_go(sm, ia, hbase + 16 + c15, g01[it][0], g01[it][1]);
    store_go(sm, ib, hbase + c15,      g10[it][0], g10[it][1]);
    store_go(sm, ib, hbase + 16 + c15, g11[it][0], g11[it][1]);
  }
  __syncthreads();

  // ---- phase 3: out = GO @ Wo + bo; store out[s][r][c] ----
  #pragma unroll
  for (int t2 = 0; t2 < 2; t2++){
    const int it = wid * 2 + t2;               // i-tile 0..15
    bf16x8 aGO[8];
    #pragma unroll
    for (int kk = 0; kk < 8; kk++) aGO[kk] = lds_frag(sm, it * 16 + c15, 32 * kk + 8 * g);
    #pragma unroll 2
    for (int ct = 0; ct < 16; ct++){
      f32x4 acc{0,0,0,0};
      #pragma unroll
      for (int kk = 0; kk < 8; kk++)
        acc = mfma16(aGO[kk], ldg_frag(WoT, ct * 16 + c15, 32 * kk + 8 * g), acc);
      const float bov = bo[ct * 16 + c15];
      const int i0 = it * 16 + g * 4;
      const int cc = ct * 16 + c15;
      out[(i0 + 0) * 65536 + r * 256 + cc] = acc.x + bov;
      out[(i0 + 1) * 65536 + r * 256 + cc] = acc.y + bov;
      out[(i0 + 2) * 65536 + r * 256 + cc] = acc.z + bov;
      out[(i0 + 3) * 65536 + r * 256 + cc] = acc.w + bov;
    }
  }
}

extern "C" void kernel_launch(void* const* d_in, const int* in_sizes, int n_in,
                              void* d_out, int out_size, void* d_ws, size_t ws_size,
                              hipStream_t stream)
{
  (void)in_sizes; (void)n_in; (void)out_size; (void)ws_size;
  const float* msa = (const float*)d_in[0];
  const float* lnw = (const float*)d_in[1];
  const float* lnb = (const float*)d_in[2];
  const float* Wq  = (const float*)d_in[3];
  const float* Wk  = (const float*)d_in[4];
  const float* Wv  = (const float*)d_in[5];
  const float* Wg  = (const float*)d_in[6];
  const float* bg  = (const float*)d_in[7];
  const float* Wo  = (const float*)d_in[8];
  const float* bo  = (const float*)d_in[9];
  short* ws = (short*)d_ws;                    // 5*65536*2 = 640 KB scratch

  prep_weights<<<256, 256, 0, stream>>>(Wq, Wk, Wv, Wg, Wo, ws);
  msa_attn<<<256, 512, 133120, stream>>>(msa, lnw, lnb, bg, bo, ws, (float*)d_out);
}